// Round 10
// baseline (134.586 us; speedup 1.0000x reference)
//
#include <hip/hip_runtime.h>
#include <hip/hip_bf16.h>

#define B_ 2
#define T_ 2048
#define C_ 1024
#define H_ 16
#define D_ 64
#define M1 4096
#define N1 3072
#define K_ 1024

typedef __attribute__((ext_vector_type(8))) __bf16 bf16x8;
typedef __attribute__((ext_vector_type(4))) float f32x4;
typedef __attribute__((ext_vector_type(8))) unsigned short ushort8_t;
typedef __attribute__((ext_vector_type(4))) unsigned short ushort4_t;
typedef __attribute__((ext_vector_type(2))) unsigned int uint2_t;

static __device__ __forceinline__ unsigned short f2bf(float f) {
    unsigned int u = __builtin_bit_cast(unsigned int, f);
    u += 0x7fffu + ((u >> 16) & 1u);
    return (unsigned short)(u >> 16);
}
static __device__ __forceinline__ unsigned short f2bf_hw(float f) {
    return __builtin_bit_cast(unsigned short, (__bf16)f);
}
static __device__ __forceinline__ unsigned int packbf(float lo, float hi) {
    return (unsigned int)f2bf_hw(lo) | ((unsigned int)f2bf_hw(hi) << 16);
}
static __device__ __forceinline__ bf16x8 bload(const unsigned short* p) {
    return __builtin_bit_cast(bf16x8, *(const ushort8_t*)p);
}

// fast exp2 -> v_exp_f32
#if defined(__has_builtin)
#if __has_builtin(__builtin_amdgcn_exp2f)
#define HAVE_EXP2_BUILTIN 1
#endif
#endif
static __device__ __forceinline__ float fexp2(float x) {
#ifdef HAVE_EXP2_BUILTIN
    return __builtin_amdgcn_exp2f(x);
#else
    float r; asm("v_exp_f32 %0, %1" : "=v"(r) : "v"(x)); return r;
#endif
}

// ---- async global->LDS (16B per lane; LDS dest wave-uniform base + lane*16) ----
typedef __attribute__((address_space(1))) const unsigned int gu32;
typedef __attribute__((address_space(3))) unsigned int lu32;
static __device__ __forceinline__ void gld16(const void* g, void* l) {
    __builtin_amdgcn_global_load_lds((gu32*)g, (lu32*)l, 16, 0, 0);
}

#define VMCNT(n) asm volatile("s_waitcnt vmcnt(" #n ")" ::: "memory")
#define LGKM0    asm volatile("s_waitcnt lgkmcnt(0)" ::: "memory")

// ---------------- cast x -> bf16 ----------------
__global__ void cast_x_kernel(const float* __restrict__ in,
                              unsigned short* __restrict__ out, int n4) {
    int idx = blockIdx.x * blockDim.x + threadIdx.x;
    int stride = gridDim.x * blockDim.x;
    for (int i = idx; i < n4; i += stride) {
        float4 v = ((const float4*)in)[i];
        ushort4_t o;
        o.x = f2bf(v.x); o.y = f2bf(v.y); o.z = f2bf(v.z); o.w = f2bf(v.w);
        ((ushort4_t*)out)[i] = o;
    }
}

// ------------- transpose f32[K][N] -> bf16[N][K] -------------
__global__ void transpose_cast_kernel(const float* __restrict__ in,
                                      unsigned short* __restrict__ out,
                                      int K, int N) {
    __shared__ float tile[32][33];
    int tx = threadIdx.x & 31;
    int ty = threadIdx.x >> 5;
    int n0 = blockIdx.x * 32;
    int k0 = blockIdx.y * 32;
#pragma unroll
    for (int rr = 0; rr < 32; rr += 8)
        tile[ty + rr][tx] = in[(size_t)(k0 + ty + rr) * N + n0 + tx];
    __syncthreads();
#pragma unroll
    for (int rr = 0; rr < 32; rr += 8)
        out[(size_t)(n0 + ty + rr) * K + k0 + tx] = f2bf(tile[tx][ty + rr]);
}

// =================== GEMM common body (dbuf LDS via global_load_lds) ===================
// SWAPPED mfma: acc[m][n] = mfma(bfv[n], af[m], .) -> lane cl owns output ROW
// i = row0+wr+m*16+cl; in-register r-axis = consecutive j = col0+wc+n*16+g*4+r.
// Epilogues get 4 consecutive output columns per lane -> wide stores.

#define GEMM_PROLOGUE(BXE, BYE)                                                          \
    __shared__ unsigned short As[2][128 * 32];                                           \
    __shared__ unsigned short Bs[2][128 * 32];                                           \
    const int tid = threadIdx.x;                                                         \
    const int lane = tid & 63;                                                           \
    const int wave = tid >> 6;                                                           \
    const int g = lane >> 4, cl = lane & 15;                                             \
    const int wr = (wave >> 1) * 64, wc = (wave & 1) * 64;                               \
    const int row0 = (BXE) * 128;                                                        \
    const int col0 = (BYE) * 128;                                                        \
    const int srow = tid >> 2;  /* 0..63 */                                              \
    const int sgran = tid & 3;                                                           \
    f32x4 acc[4][4];                                                                     \
    _Pragma("unroll") for (int m = 0; m < 4; ++m)                                        \
        _Pragma("unroll") for (int n = 0; n < 4; ++n)                                    \
            acc[m][n] = (f32x4){0.f, 0.f, 0.f, 0.f};                                     \
    auto stage = [&](int buf, int k0) {                                                  \
        _Pragma("unroll") for (int c = 0; c < 2; ++c) {                                  \
            int r = srow + c * 64;                                                       \
            gld16(A + (size_t)(row0 + r) * K_ + k0 + sgran * 8,                          \
                  (char*)&As[buf][0] + c * 4096 + wave * 1024);                          \
            gld16(Bt + (size_t)(col0 + r) * K_ + k0 + sgran * 8,                         \
                  (char*)&Bs[buf][0] + c * 4096 + wave * 1024);                          \
        }                                                                                \
    };                                                                                   \
    stage(0, 0);                                                                         \
    int buf = 0;                                                                         \
    for (int k0 = 0; k0 < K_; k0 += 32) {                                                \
        if (k0 + 32 < K_) { stage(buf ^ 1, k0 + 32); VMCNT(4); }                         \
        else              { VMCNT(0); }                                                  \
        __builtin_amdgcn_s_barrier();                                                    \
        bf16x8 af[4], bfv[4];                                                            \
        _Pragma("unroll") for (int m = 0; m < 4; ++m)                                    \
            af[m] = bload(&As[buf][(wr + m * 16 + cl) * 32 + g * 8]);                    \
        _Pragma("unroll") for (int n = 0; n < 4; ++n)                                    \
            bfv[n] = bload(&Bs[buf][(wc + n * 16 + cl) * 32 + g * 8]);                   \
        _Pragma("unroll") for (int m = 0; m < 4; ++m)                                    \
            _Pragma("unroll") for (int n = 0; n < 4; ++n)                                \
                acc[m][n] = __builtin_amdgcn_mfma_f32_16x16x32_bf16(                     \
                    bfv[n], af[m], acc[m][n], 0, 0, 0);                                  \
        LGKM0;                                                                           \
        __builtin_amdgcn_s_barrier();                                                    \
        buf ^= 1;                                                                        \
    }

// ---------------- GEMM1: qkv = Xb @ Wt1^T + b ----------------
// XCD-chunked block map: per-XCD 8-row x 12-col region. Each wave's 64-col
// span (col0+wc .. +63) is exactly ONE head -> which/h wave-uniform.
__global__ __launch_bounds__(256)
void gemm_qkv_kernel(const unsigned short* __restrict__ A,   // [4096][1024] bf16
                     const unsigned short* __restrict__ Bt,  // [3072][1024] bf16
                     const float* __restrict__ bias,         // [3072]
                     unsigned short* __restrict__ Qo,        // [BH][T][D] (pre-scaled)
                     unsigned short* __restrict__ Ko,        // [BH][T][D]
                     unsigned short* __restrict__ Vt)        // [BH][D][T]
{
    const int lin = blockIdx.x + gridDim.x * blockIdx.y;  // 0..767
    const int xcd = lin & 7;
    const int idx = lin >> 3;                              // 0..95
    const int bx = (xcd >> 1) * 8 + (idx & 7);             // 0..31
    const int by = (xcd & 1) * 12 + (idx >> 3);            // 0..23

    GEMM_PROLOGUE(bx, by)

    const float QSCALE = 0.125f * 1.44269504088896340736f;  // 1/sqrt(D) * log2(e)
    const int jbase = col0 + wc;           // multiple of 64
    const int which = jbase >> 10;         // wave-uniform
    const int h = (jbase & 1023) >> 6;     // wave-uniform
#pragma unroll
    for (int m = 0; m < 4; ++m) {
        int i = row0 + wr + m * 16 + cl;
        int b = i >> 11, t = i & 2047;
        size_t bh = (size_t)(b * H_ + h);
#pragma unroll
        for (int n = 0; n < 4; ++n) {
            int d0 = n * 16 + g * 4;
            float4 bv = *(const float4*)&bias[jbase + d0];
            float v0 = acc[m][n][0] + bv.x;
            float v1 = acc[m][n][1] + bv.y;
            float v2 = acc[m][n][2] + bv.z;
            float v3 = acc[m][n][3] + bv.w;
            if (which == 0) {
                uint2_t w;
                w.x = packbf(v0 * QSCALE, v1 * QSCALE);
                w.y = packbf(v2 * QSCALE, v3 * QSCALE);
                *(uint2_t*)&Qo[(bh * T_ + t) * D_ + d0] = w;
            } else if (which == 1) {
                uint2_t w;
                w.x = packbf(v0, v1);
                w.y = packbf(v2, v3);
                *(uint2_t*)&Ko[(bh * T_ + t) * D_ + d0] = w;
            } else {
                Vt[(bh * D_ + d0 + 0) * T_ + t] = f2bf_hw(v0);
                Vt[(bh * D_ + d0 + 1) * T_ + t] = f2bf_hw(v1);
                Vt[(bh * D_ + d0 + 2) * T_ + t] = f2bf_hw(v2);
                Vt[(bh * D_ + d0 + 3) * T_ + t] = f2bf_hw(v3);
            }
        }
    }
}

// ---------------- GEMM2: out = AO @ Wt2^T + b (fp32 out) ----------------
__global__ __launch_bounds__(256)
void gemm_proj_kernel(const unsigned short* __restrict__ A,   // [4096][1024] bf16
                      const unsigned short* __restrict__ Bt,  // [1024][1024] bf16
                      const float* __restrict__ bias,         // [1024]
                      float* __restrict__ out)                // [4096][1024] f32
{
    GEMM_PROLOGUE(blockIdx.x, blockIdx.y)

#pragma unroll
    for (int m = 0; m < 4; ++m) {
        int i = row0 + wr + m * 16 + cl;
#pragma unroll
        for (int n = 0; n < 4; ++n) {
            int j0 = col0 + wc + n * 16 + g * 4;
            float4 bv = *(const float4*)&bias[j0];
            f32x4 o = acc[m][n];
            o[0] += bv.x; o[1] += bv.y; o[2] += bv.z; o[3] += bv.w;
            *(f32x4*)&out[(size_t)i * C_ + j0] = o;
        }
    }
}

// ---------------- flash attention (causal, swapped QK^T, 4 blocks/CU) ----------------
// grid 1024 (1-D): xcd = lin&7; bh = xcd + 8*(idx&3) -> 4 heads/XCD (L2-resident);
// qt = 31-(idx>>2) -> longest tiles dispatch first. LDS 40960 B = 4 blocks/CU.
// Swapped operands: lane owns q-row. Softmax: balanced trees + defer-max (THR=8).
__global__ __launch_bounds__(256)
void attn_kernel(const unsigned short* __restrict__ Q,   // [BH][T][D], pre-scaled
                 const unsigned short* __restrict__ Kb,  // [BH][T][D]
                 const unsigned short* __restrict__ Vh_, // [BH][D][T]
                 unsigned short* __restrict__ AO)        // [B][T][C] bf16
{
    __shared__ unsigned short Klds[2][64 * 64];   // 16 KB
    __shared__ unsigned short Vlds[2][64 * 64];   // 16 KB
    __shared__ unsigned short Plds[4][16 * 64];   // 8 KB, XOR-swizzled rows
    const int lin = blockIdx.x;                   // 0..1023
    const int idx = lin >> 3;                     // 0..127
    const int bh  = (lin & 7) + 8 * (idx & 3);    // 0..31, head pinned to one XCD
    const int qt  = 31 - (idx >> 2);              // long tiles first
    const int b = bh >> 4, h = bh & 15;
    const int tid = threadIdx.x;
    const int lane = tid & 63;
    const int wave = tid >> 6;
    const int g = lane >> 4, cl = lane & 15;

    const unsigned short* Qh = Q + (size_t)bh * T_ * D_;
    const unsigned short* Kh = Kb + (size_t)bh * T_ * D_;
    const unsigned short* Vh = Vh_ + (size_t)bh * D_ * T_;

    const int srow = tid >> 3;  // 0..31
    const int sg   = tid & 7;
    const int pswz = (cl & 7) << 4;   // Plds byte-XOR (same involution write & read)

    auto stage = [&](int bufi, int kb) {
#pragma unroll
        for (int c = 0; c < 2; ++c) {
            int r = srow + c * 32;
            int lg = sg ^ (r & 7);
            gld16(Kh + (size_t)(kb + r) * D_ + lg * 8,
                  (char*)&Klds[bufi][0] + c * 4096 + wave * 1024);
            gld16(Vh + (size_t)r * T_ + kb + lg * 8,
                  (char*)&Vlds[bufi][0] + c * 4096 + wave * 1024);
        }
    };

    const int q0 = qt * 64 + wave * 16;
    const int tq = q0 + cl;   // this lane's q row

    bf16x8 qf[2];
#pragma unroll
    for (int c2 = 0; c2 < 2; ++c2)
        qf[c2] = bload(Qh + (size_t)(q0 + cl) * D_ + c2 * 32 + g * 8);

    f32x4 oacc[4];
#pragma unroll
    for (int n = 0; n < 4; ++n) oacc[n] = (f32x4){0.f, 0.f, 0.f, 0.f};
    float m_run = -INFINITY, l_run = 0.f;

    const int nk = qt + 1;
    stage(0, 0);
    int buf = 0;
    for (int kt = 0; kt < nk; ++kt) {
        if (kt + 1 < nk) { stage(buf ^ 1, (kt + 1) * 64); VMCNT(4); }
        else             { VMCNT(0); }
        __builtin_amdgcn_s_barrier();

        const int kb = kt * 64;
        // ---- QK^T (swapped): sc[n] row = k, col = q ----
        f32x4 sc[4];
        __builtin_amdgcn_s_setprio(1);
#pragma unroll
        for (int n = 0; n < 4; ++n) {
            sc[n] = (f32x4){0.f, 0.f, 0.f, 0.f};
#pragma unroll
            for (int c2 = 0; c2 < 2; ++c2) {
                int pg = (c2 * 4 + g) ^ (cl & 7);
                bf16x8 kf = bload(&Klds[buf][(n * 16 + cl) * 64 + pg * 8]);
                sc[n] = __builtin_amdgcn_mfma_f32_16x16x32_bf16(kf, qf[c2], sc[n], 0, 0, 0);
            }
        }
        __builtin_amdgcn_s_setprio(0);
        // ---- causal mask (diagonal tile only); k = kb + n*16 + g*4 + r ----
        if (kt == qt) {
#pragma unroll
            for (int n = 0; n < 4; ++n) {
                int k4 = kb + n * 16 + g * 4;
#pragma unroll
                for (int r = 0; r < 4; ++r)
                    if (k4 + r > tq) sc[n][r] = -INFINITY;
            }
        }
        // ---- online softmax: balanced trees + defer-max (THR=8) ----
        float mx[4];
#pragma unroll
        for (int n = 0; n < 4; ++n)
            mx[n] = fmaxf(fmaxf(sc[n][0], sc[n][1]), fmaxf(sc[n][2], sc[n][3]));
        float vmax = fmaxf(fmaxf(mx[0], mx[1]), fmaxf(mx[2], mx[3]));
        vmax = fmaxf(vmax, __shfl_xor(vmax, 16, 64));
        vmax = fmaxf(vmax, __shfl_xor(vmax, 32, 64));
        if (!__all(vmax <= m_run + 8.f)) {
            float mn = fmaxf(m_run, vmax);
            float alpha = fexp2(m_run - mn);
            l_run *= alpha;
#pragma unroll
            for (int n = 0; n < 4; ++n)
#pragma unroll
                for (int r = 0; r < 4; ++r) oacc[n][r] *= alpha;
            m_run = mn;
        }
        float p[4][4], psub[4];
#pragma unroll
        for (int n = 0; n < 4; ++n) {
#pragma unroll
            for (int r = 0; r < 4; ++r) p[n][r] = fexp2(sc[n][r] - m_run);
            psub[n] = (p[n][0] + p[n][1]) + (p[n][2] + p[n][3]);
        }
        float ps = (psub[0] + psub[1]) + (psub[2] + psub[3]);
        ps += __shfl_xor(ps, 16, 64);
        ps += __shfl_xor(ps, 32, 64);
        l_run += ps;
        // ---- P: pack bf16 pairs, 4x ds_write_b64 into own (swizzled) q-row ----
#pragma unroll
        for (int n = 0; n < 4; ++n) {
            uint2_t w;
            w.x = packbf(p[n][0], p[n][1]);
            w.y = packbf(p[n][2], p[n][3]);
            *(uint2_t*)((char*)&Plds[wave][0] + ((cl * 128 + n * 32 + g * 8) ^ pswz)) = w;
        }
        bf16x8 pf[2];
#pragma unroll
        for (int kk = 0; kk < 2; ++kk)
            pf[kk] = bload((const unsigned short*)
                ((char*)&Plds[wave][0] + ((cl * 128 + kk * 64 + g * 16) ^ pswz)));
        // ---- PV (swapped): O^T += mfma(V^T-frag, P^T-frag) ----
        __builtin_amdgcn_s_setprio(1);
#pragma unroll
        for (int n = 0; n < 4; ++n) {
#pragma unroll
            for (int kk = 0; kk < 2; ++kk) {
                int pg = (kk * 4 + g) ^ (cl & 7);
                bf16x8 vfr = bload(&Vlds[buf][(n * 16 + cl) * 64 + pg * 8]);
                oacc[n] = __builtin_amdgcn_mfma_f32_16x16x32_bf16(vfr, pf[kk], oacc[n], 0, 0, 0);
            }
        }
        __builtin_amdgcn_s_setprio(0);
        LGKM0;
        __builtin_amdgcn_s_barrier();
        buf ^= 1;
    }
    // ---- epilogue: lane owns row t = q0+cl; d = n*16 + g*4 + r ----
    float inv = 1.f / l_run;
#pragma unroll
    for (int n = 0; n < 4; ++n) {
        uint2_t w;
        w.x = packbf(oacc[n][0] * inv, oacc[n][1] * inv);
        w.y = packbf(oacc[n][2] * inv, oacc[n][3] * inv);
        *(uint2_t*)&AO[((size_t)b * T_ + tq) * C_ + h * D_ + n * 16 + g * 4] = w;
    }
}

extern "C" void kernel_launch(void* const* d_in, const int* in_sizes, int n_in,
                              void* d_out, int out_size, void* d_ws, size_t ws_size,
                              hipStream_t stream) {
    (void)in_sizes; (void)n_in; (void)out_size; (void)ws_size;
    const float* x      = (const float*)d_in[0];
    const float* w_attn = (const float*)d_in[1];
    const float* b_attn = (const float*)d_in[2];
    const float* w_proj = (const float*)d_in[3];
    const float* b_proj = (const float*)d_in[4];
    float* out = (float*)d_out;

    char* ws = (char*)d_ws;
    unsigned short* Xb  = (unsigned short*)(ws);
    unsigned short* Wt1 = (unsigned short*)(ws + ((size_t)8  << 20));
    unsigned short* Wt2 = (unsigned short*)(ws + ((size_t)14 << 20));
    unsigned short* Qb  = (unsigned short*)(ws + ((size_t)16 << 20));
    unsigned short* Kb  = (unsigned short*)(ws + ((size_t)24 << 20));
    unsigned short* Vt  = (unsigned short*)(ws + ((size_t)32 << 20));
    unsigned short* AO  = Xb;  // Xb dead after gemm_qkv

    cast_x_kernel<<<1024, 256, 0, stream>>>(x, Xb, (M1 * K_) / 4);
    transpose_cast_kernel<<<dim3(N1 / 32, K_ / 32), 256, 0, stream>>>(w_attn, Wt1, K_, N1);
    transpose_cast_kernel<<<dim3(C_ / 32, K_ / 32), 256, 0, stream>>>(w_proj, Wt2, K_, C_);
    gemm_qkv_kernel<<<dim3(M1 / 128, N1 / 128), 256, 0, stream>>>(Xb, Wt1, b_attn, Qb, Kb, Vt);
    attn_kernel<<<1024, 256, 0, stream>>>(Qb, Kb, Vt, AO);
    gemm_proj_kernel<<<dim3(M1 / 128, C_ / 128), 256, 0, stream>>>(AO, Wt2, b_proj, out);
}

// Round 11
// 123.824 us; speedup vs baseline: 1.0869x; 1.0869x over previous
//
#include <hip/hip_runtime.h>
#include <hip/hip_bf16.h>

#define B_ 2
#define T_ 2048
#define C_ 1024
#define H_ 16
#define D_ 64
#define M1 4096
#define N1 3072
#define K_ 1024

typedef __attribute__((ext_vector_type(8))) __bf16 bf16x8;
typedef __attribute__((ext_vector_type(4))) float f32x4;
typedef __attribute__((ext_vector_type(8))) unsigned short ushort8_t;
typedef __attribute__((ext_vector_type(4))) unsigned short ushort4_t;
typedef __attribute__((ext_vector_type(2))) unsigned int uint2_t;

static __device__ __forceinline__ unsigned short f2bf(float f) {
    unsigned int u = __builtin_bit_cast(unsigned int, f);
    u += 0x7fffu + ((u >> 16) & 1u);
    return (unsigned short)(u >> 16);
}
static __device__ __forceinline__ unsigned short f2bf_hw(float f) {
    return __builtin_bit_cast(unsigned short, (__bf16)f);
}
static __device__ __forceinline__ unsigned int packbf(float lo, float hi) {
    return (unsigned int)f2bf_hw(lo) | ((unsigned int)f2bf_hw(hi) << 16);
}
static __device__ __forceinline__ bf16x8 bload(const unsigned short* p) {
    return __builtin_bit_cast(bf16x8, *(const ushort8_t*)p);
}

// fast exp2 -> v_exp_f32
#if defined(__has_builtin)
#if __has_builtin(__builtin_amdgcn_exp2f)
#define HAVE_EXP2_BUILTIN 1
#endif
#endif
static __device__ __forceinline__ float fexp2(float x) {
#ifdef HAVE_EXP2_BUILTIN
    return __builtin_amdgcn_exp2f(x);
#else
    float r; asm("v_exp_f32 %0, %1" : "=v"(r) : "v"(x)); return r;
#endif
}

// ---- async global->LDS (16B per lane; LDS dest wave-uniform base + lane*16) ----
typedef __attribute__((address_space(1))) const unsigned int gu32;
typedef __attribute__((address_space(3))) unsigned int lu32;
static __device__ __forceinline__ void gld16(const void* g, void* l) {
    __builtin_amdgcn_global_load_lds((gu32*)g, (lu32*)l, 16, 0, 0);
}

#define VMCNT(n) asm volatile("s_waitcnt vmcnt(" #n ")" ::: "memory")
#define LGKM0    asm volatile("s_waitcnt lgkmcnt(0)" ::: "memory")

// ---------------- cast x -> bf16 ----------------
__global__ void cast_x_kernel(const float* __restrict__ in,
                              unsigned short* __restrict__ out, int n4) {
    int idx = blockIdx.x * blockDim.x + threadIdx.x;
    int stride = gridDim.x * blockDim.x;
    for (int i = idx; i < n4; i += stride) {
        float4 v = ((const float4*)in)[i];
        ushort4_t o;
        o.x = f2bf(v.x); o.y = f2bf(v.y); o.z = f2bf(v.z); o.w = f2bf(v.w);
        ((ushort4_t*)out)[i] = o;
    }
}

// ------------- transpose f32[K][N] -> bf16[N][K] -------------
__global__ void transpose_cast_kernel(const float* __restrict__ in,
                                      unsigned short* __restrict__ out,
                                      int K, int N) {
    __shared__ float tile[32][33];
    int tx = threadIdx.x & 31;
    int ty = threadIdx.x >> 5;
    int n0 = blockIdx.x * 32;
    int k0 = blockIdx.y * 32;
#pragma unroll
    for (int rr = 0; rr < 32; rr += 8)
        tile[ty + rr][tx] = in[(size_t)(k0 + ty + rr) * N + n0 + tx];
    __syncthreads();
#pragma unroll
    for (int rr = 0; rr < 32; rr += 8)
        out[(size_t)(n0 + ty + rr) * K + k0 + tx] = f2bf(tile[tx][ty + rr]);
}

// =================== GEMM common body (dbuf LDS via global_load_lds) ===================
// Granule XOR-swizzle: LDS slot s of row r holds global granule s ^ ((r>>1)&3);
// quad index (4r + slot) % 8 then covers all 8 quads over any 8 fragment rows ->
// conflict-free ds_read_b128 (was 8-way). Source pre-swizzled, dest linear (rule #21).
// Unswapped mfma(af, bfv): lane cl owns output COLUMN j; r-axis = row (t).

#define GEMM_PROLOGUE(BXE, BYE)                                                          \
    __shared__ unsigned short As[2][128 * 32];                                           \
    __shared__ unsigned short Bs[2][128 * 32];                                           \
    const int tid = threadIdx.x;                                                         \
    const int lane = tid & 63;                                                           \
    const int wave = tid >> 6;                                                           \
    const int g = lane >> 4, cl = lane & 15;                                             \
    const int wr = (wave >> 1) * 64, wc = (wave & 1) * 64;                               \
    const int row0 = (BXE) * 128;                                                        \
    const int col0 = (BYE) * 128;                                                        \
    const int srow = tid >> 2;  /* 0..63 */                                              \
    const int sgran = tid & 3;                                                           \
    f32x4 acc[4][4];                                                                     \
    _Pragma("unroll") for (int m = 0; m < 4; ++m)                                        \
        _Pragma("unroll") for (int n = 0; n < 4; ++n)                                    \
            acc[m][n] = (f32x4){0.f, 0.f, 0.f, 0.f};                                     \
    auto stage = [&](int buf, int k0) {                                                  \
        _Pragma("unroll") for (int c = 0; c < 2; ++c) {                                  \
            int r = srow + c * 64;                                                       \
            int lg = sgran ^ ((r >> 1) & 3);                                             \
            gld16(A + (size_t)(row0 + r) * K_ + k0 + lg * 8,                             \
                  (char*)&As[buf][0] + c * 4096 + wave * 1024);                          \
            gld16(Bt + (size_t)(col0 + r) * K_ + k0 + lg * 8,                            \
                  (char*)&Bs[buf][0] + c * 4096 + wave * 1024);                          \
        }                                                                                \
    };                                                                                   \
    stage(0, 0);                                                                         \
    int buf = 0;                                                                         \
    for (int k0 = 0; k0 < K_; k0 += 32) {                                                \
        if (k0 + 32 < K_) { stage(buf ^ 1, k0 + 32); VMCNT(4); }                         \
        else              { VMCNT(0); }                                                  \
        __builtin_amdgcn_s_barrier();                                                    \
        bf16x8 af[4], bfv[4];                                                            \
        _Pragma("unroll") for (int m = 0; m < 4; ++m) {                                  \
            int ra = wr + m * 16 + cl;                                                   \
            af[m] = bload(&As[buf][ra * 32 + (g ^ ((ra >> 1) & 3)) * 8]);                \
        }                                                                                \
        _Pragma("unroll") for (int n = 0; n < 4; ++n) {                                  \
            int rb = wc + n * 16 + cl;                                                   \
            bfv[n] = bload(&Bs[buf][rb * 32 + (g ^ ((rb >> 1) & 3)) * 8]);               \
        }                                                                                \
        _Pragma("unroll") for (int m = 0; m < 4; ++m)                                    \
            _Pragma("unroll") for (int n = 0; n < 4; ++n)                                \
                acc[m][n] = __builtin_amdgcn_mfma_f32_16x16x32_bf16(                     \
                    af[m], bfv[n], acc[m][n], 0, 0, 0);                                  \
        LGKM0;                                                                           \
        __builtin_amdgcn_s_barrier();                                                    \
        buf ^= 1;                                                                        \
    }

// ---------------- GEMM1: qkv = Xb @ Wt1^T + b ----------------
// XCD-chunked block map: per-XCD 8-row x 12-col region. Lane owns col j (fixed
// d per lane); r-axis = 4 consecutive t -> V^T store is one packed 8B write.
__global__ __launch_bounds__(256)
void gemm_qkv_kernel(const unsigned short* __restrict__ A,   // [4096][1024] bf16
                     const unsigned short* __restrict__ Bt,  // [3072][1024] bf16
                     const float* __restrict__ bias,         // [3072]
                     unsigned short* __restrict__ Qo,        // [BH][T][D] (pre-scaled)
                     unsigned short* __restrict__ Ko,        // [BH][T][D]
                     unsigned short* __restrict__ Vt)        // [BH][D][T]
{
    const int lin = blockIdx.x + gridDim.x * blockIdx.y;  // 0..767
    const int xcd = lin & 7;
    const int idx = lin >> 3;                              // 0..95
    const int bx = (xcd >> 1) * 8 + (idx & 7);             // 0..31
    const int by = (xcd & 1) * 12 + (idx >> 3);            // 0..23

    GEMM_PROLOGUE(bx, by)

    const float QSCALE = 0.125f * 1.44269504088896340736f;  // 1/sqrt(D) * log2(e)
#pragma unroll
    for (int m = 0; m < 4; ++m) {
        int i0 = row0 + wr + m * 16 + g * 4;
        int b = i0 >> 11, t0 = i0 & 2047;   // 4 consecutive t from t0 (same b)
#pragma unroll
        for (int n = 0; n < 4; ++n) {
            int j = col0 + wc + n * 16 + cl;
            int which = j >> 10;             // wave-uniform in practice
            int c = j & 1023;
            int h = c >> 6, d = c & 63;
            float bv = bias[j];
            size_t bh = (size_t)(b * H_ + h);
            float v0 = acc[m][n][0] + bv;
            float v1 = acc[m][n][1] + bv;
            float v2 = acc[m][n][2] + bv;
            float v3 = acc[m][n][3] + bv;
            if (which == 2) {
                uint2_t w;
                w.x = packbf(v0, v1);
                w.y = packbf(v2, v3);
                *(uint2_t*)&Vt[(bh * D_ + d) * T_ + t0] = w;
            } else if (which == 0) {
                Qo[(bh * T_ + t0 + 0) * D_ + d] = f2bf_hw(v0 * QSCALE);
                Qo[(bh * T_ + t0 + 1) * D_ + d] = f2bf_hw(v1 * QSCALE);
                Qo[(bh * T_ + t0 + 2) * D_ + d] = f2bf_hw(v2 * QSCALE);
                Qo[(bh * T_ + t0 + 3) * D_ + d] = f2bf_hw(v3 * QSCALE);
            } else {
                Ko[(bh * T_ + t0 + 0) * D_ + d] = f2bf_hw(v0);
                Ko[(bh * T_ + t0 + 1) * D_ + d] = f2bf_hw(v1);
                Ko[(bh * T_ + t0 + 2) * D_ + d] = f2bf_hw(v2);
                Ko[(bh * T_ + t0 + 3) * D_ + d] = f2bf_hw(v3);
            }
        }
    }
}

// ---------------- GEMM2: out = AO @ Wt2^T + b (fp32 out) ----------------
__global__ __launch_bounds__(256)
void gemm_proj_kernel(const unsigned short* __restrict__ A,   // [4096][1024] bf16
                      const unsigned short* __restrict__ Bt,  // [1024][1024] bf16
                      const float* __restrict__ bias,         // [1024]
                      float* __restrict__ out)                // [4096][1024] f32
{
    GEMM_PROLOGUE(blockIdx.x, blockIdx.y)

#pragma unroll
    for (int m = 0; m < 4; ++m) {
        int i0 = row0 + wr + m * 16 + g * 4;
#pragma unroll
        for (int n = 0; n < 4; ++n) {
            int j = col0 + wc + n * 16 + cl;
            float bv = bias[j];
#pragma unroll
            for (int r = 0; r < 4; ++r)
                out[(size_t)(i0 + r) * C_ + j] = acc[m][n][r] + bv;
        }
    }
}

// ---------------- flash attention (causal, swapped QK^T, 4 blocks/CU) ----------------
// grid 1024 (1-D): xcd = lin&7; bh = xcd + 8*(idx&3) -> 4 heads/XCD (L2-resident);
// qt = 31-(idx>>2) -> longest tiles dispatch first. LDS 40960 B = 4 blocks/CU.
// Swapped operands: lane owns q-row. Softmax: balanced trees + defer-max (THR=8).
__global__ __launch_bounds__(256)
void attn_kernel(const unsigned short* __restrict__ Q,   // [BH][T][D], pre-scaled
                 const unsigned short* __restrict__ Kb,  // [BH][T][D]
                 const unsigned short* __restrict__ Vh_, // [BH][D][T]
                 unsigned short* __restrict__ AO)        // [B][T][C] bf16
{
    __shared__ unsigned short Klds[2][64 * 64];   // 16 KB
    __shared__ unsigned short Vlds[2][64 * 64];   // 16 KB
    __shared__ unsigned short Plds[4][16 * 64];   // 8 KB, XOR-swizzled rows
    const int lin = blockIdx.x;                   // 0..1023
    const int idx = lin >> 3;                     // 0..127
    const int bh  = (lin & 7) + 8 * (idx & 3);    // 0..31, head pinned to one XCD
    const int qt  = 31 - (idx >> 2);              // long tiles first
    const int b = bh >> 4, h = bh & 15;
    const int tid = threadIdx.x;
    const int lane = tid & 63;
    const int wave = tid >> 6;
    const int g = lane >> 4, cl = lane & 15;

    const unsigned short* Qh = Q + (size_t)bh * T_ * D_;
    const unsigned short* Kh = Kb + (size_t)bh * T_ * D_;
    const unsigned short* Vh = Vh_ + (size_t)bh * D_ * T_;

    const int srow = tid >> 3;  // 0..31
    const int sg   = tid & 7;
    const int pswz = (cl & 7) << 4;   // Plds byte-XOR (same involution write & read)

    auto stage = [&](int bufi, int kb) {
#pragma unroll
        for (int c = 0; c < 2; ++c) {
            int r = srow + c * 32;
            int lg = sg ^ (r & 7);
            gld16(Kh + (size_t)(kb + r) * D_ + lg * 8,
                  (char*)&Klds[bufi][0] + c * 4096 + wave * 1024);
            gld16(Vh + (size_t)r * T_ + kb + lg * 8,
                  (char*)&Vlds[bufi][0] + c * 4096 + wave * 1024);
        }
    };

    const int q0 = qt * 64 + wave * 16;
    const int tq = q0 + cl;   // this lane's q row

    bf16x8 qf[2];
#pragma unroll
    for (int c2 = 0; c2 < 2; ++c2)
        qf[c2] = bload(Qh + (size_t)(q0 + cl) * D_ + c2 * 32 + g * 8);

    f32x4 oacc[4];
#pragma unroll
    for (int n = 0; n < 4; ++n) oacc[n] = (f32x4){0.f, 0.f, 0.f, 0.f};
    float m_run = -INFINITY, l_run = 0.f;

    const int nk = qt + 1;
    stage(0, 0);
    int buf = 0;
    for (int kt = 0; kt < nk; ++kt) {
        if (kt + 1 < nk) { stage(buf ^ 1, (kt + 1) * 64); VMCNT(4); }
        else             { VMCNT(0); }
        __builtin_amdgcn_s_barrier();

        const int kb = kt * 64;
        // ---- QK^T (swapped): sc[n] row = k, col = q ----
        f32x4 sc[4];
        __builtin_amdgcn_s_setprio(1);
#pragma unroll
        for (int n = 0; n < 4; ++n) {
            sc[n] = (f32x4){0.f, 0.f, 0.f, 0.f};
#pragma unroll
            for (int c2 = 0; c2 < 2; ++c2) {
                int pg = (c2 * 4 + g) ^ (cl & 7);
                bf16x8 kf = bload(&Klds[buf][(n * 16 + cl) * 64 + pg * 8]);
                sc[n] = __builtin_amdgcn_mfma_f32_16x16x32_bf16(kf, qf[c2], sc[n], 0, 0, 0);
            }
        }
        __builtin_amdgcn_s_setprio(0);
        // ---- causal mask (diagonal tile only); k = kb + n*16 + g*4 + r ----
        if (kt == qt) {
#pragma unroll
            for (int n = 0; n < 4; ++n) {
                int k4 = kb + n * 16 + g * 4;
#pragma unroll
                for (int r = 0; r < 4; ++r)
                    if (k4 + r > tq) sc[n][r] = -INFINITY;
            }
        }
        // ---- online softmax: balanced trees + defer-max (THR=8) ----
        float mx[4];
#pragma unroll
        for (int n = 0; n < 4; ++n)
            mx[n] = fmaxf(fmaxf(sc[n][0], sc[n][1]), fmaxf(sc[n][2], sc[n][3]));
        float vmax = fmaxf(fmaxf(mx[0], mx[1]), fmaxf(mx[2], mx[3]));
        vmax = fmaxf(vmax, __shfl_xor(vmax, 16, 64));
        vmax = fmaxf(vmax, __shfl_xor(vmax, 32, 64));
        if (!__all(vmax <= m_run + 8.f)) {
            float mn = fmaxf(m_run, vmax);
            float alpha = fexp2(m_run - mn);
            l_run *= alpha;
#pragma unroll
            for (int n = 0; n < 4; ++n)
#pragma unroll
                for (int r = 0; r < 4; ++r) oacc[n][r] *= alpha;
            m_run = mn;
        }
        float p[4][4], psub[4];
#pragma unroll
        for (int n = 0; n < 4; ++n) {
#pragma unroll
            for (int r = 0; r < 4; ++r) p[n][r] = fexp2(sc[n][r] - m_run);
            psub[n] = (p[n][0] + p[n][1]) + (p[n][2] + p[n][3]);
        }
        float ps = (psub[0] + psub[1]) + (psub[2] + psub[3]);
        ps += __shfl_xor(ps, 16, 64);
        ps += __shfl_xor(ps, 32, 64);
        l_run += ps;
        // ---- P: pack bf16 pairs, 4x ds_write_b64 into own (swizzled) q-row ----
#pragma unroll
        for (int n = 0; n < 4; ++n) {
            uint2_t w;
            w.x = packbf(p[n][0], p[n][1]);
            w.y = packbf(p[n][2], p[n][3]);
            *(uint2_t*)((char*)&Plds[wave][0] + ((cl * 128 + n * 32 + g * 8) ^ pswz)) = w;
        }
        bf16x8 pf[2];
#pragma unroll
        for (int kk = 0; kk < 2; ++kk)
            pf[kk] = bload((const unsigned short*)
                ((char*)&Plds[wave][0] + ((cl * 128 + kk * 64 + g * 16) ^ pswz)));
        // ---- PV (swapped): O^T += mfma(V^T-frag, P^T-frag) ----
        __builtin_amdgcn_s_setprio(1);
#pragma unroll
        for (int n = 0; n < 4; ++n) {
#pragma unroll
            for (int kk = 0; kk < 2; ++kk) {
                int pg = (kk * 4 + g) ^ (cl & 7);
                bf16x8 vfr = bload(&Vlds[buf][(n * 16 + cl) * 64 + pg * 8]);
                oacc[n] = __builtin_amdgcn_mfma_f32_16x16x32_bf16(vfr, pf[kk], oacc[n], 0, 0, 0);
            }
        }
        __builtin_amdgcn_s_setprio(0);
        LGKM0;
        __builtin_amdgcn_s_barrier();
        buf ^= 1;
    }
    // ---- epilogue: lane owns row t = q0+cl; d = n*16 + g*4 + r ----
    float inv = 1.f / l_run;
#pragma unroll
    for (int n = 0; n < 4; ++n) {
        uint2_t w;
        w.x = packbf(oacc[n][0] * inv, oacc[n][1] * inv);
        w.y = packbf(oacc[n][2] * inv, oacc[n][3] * inv);
        *(uint2_t*)&AO[((size_t)b * T_ + tq) * C_ + h * D_ + n * 16 + g * 4] = w;
    }
}

extern "C" void kernel_launch(void* const* d_in, const int* in_sizes, int n_in,
                              void* d_out, int out_size, void* d_ws, size_t ws_size,
                              hipStream_t stream) {
    (void)in_sizes; (void)n_in; (void)out_size; (void)ws_size;
    const float* x      = (const float*)d_in[0];
    const float* w_attn = (const float*)d_in[1];
    const float* b_attn = (const float*)d_in[2];
    const float* w_proj = (const float*)d_in[3];
    const float* b_proj = (const float*)d_in[4];
    float* out = (float*)d_out;

    char* ws = (char*)d_ws;
    unsigned short* Xb  = (unsigned short*)(ws);
    unsigned short* Wt1 = (unsigned short*)(ws + ((size_t)8  << 20));
    unsigned short* Wt2 = (unsigned short*)(ws + ((size_t)14 << 20));
    unsigned short* Qb  = (unsigned short*)(ws + ((size_t)16 << 20));
    unsigned short* Kb  = (unsigned short*)(ws + ((size_t)24 << 20));
    unsigned short* Vt  = (unsigned short*)(ws + ((size_t)32 << 20));
    unsigned short* AO  = Xb;  // Xb dead after gemm_qkv

    cast_x_kernel<<<1024, 256, 0, stream>>>(x, Xb, (M1 * K_) / 4);
    transpose_cast_kernel<<<dim3(N1 / 32, K_ / 32), 256, 0, stream>>>(w_attn, Wt1, K_, N1);
    transpose_cast_kernel<<<dim3(C_ / 32, K_ / 32), 256, 0, stream>>>(w_proj, Wt2, K_, C_);
    gemm_qkv_kernel<<<dim3(M1 / 128, N1 / 128), 256, 0, stream>>>(Xb, Wt1, b_attn, Qb, Kb, Vt);
    attn_kernel<<<1024, 256, 0, stream>>>(Qb, Kb, Vt, AO);
    gemm_proj_kernel<<<dim3(M1 / 128, C_ / 128), 256, 0, stream>>>(AO, Wt2, b_proj, out);
}

// Round 12
// 120.103 us; speedup vs baseline: 1.1206x; 1.0310x over previous
//
#include <hip/hip_runtime.h>
#include <hip/hip_bf16.h>

#define B_ 2
#define T_ 2048
#define C_ 1024
#define H_ 16
#define D_ 64
#define M1 4096
#define N1 3072
#define K_ 1024

typedef __attribute__((ext_vector_type(8))) __bf16 bf16x8;
typedef __attribute__((ext_vector_type(4))) float f32x4;
typedef __attribute__((ext_vector_type(8))) unsigned short ushort8_t;
typedef __attribute__((ext_vector_type(4))) unsigned short ushort4_t;
typedef __attribute__((ext_vector_type(2))) unsigned int uint2_t;

static __device__ __forceinline__ unsigned short f2bf(float f) {
    unsigned int u = __builtin_bit_cast(unsigned int, f);
    u += 0x7fffu + ((u >> 16) & 1u);
    return (unsigned short)(u >> 16);
}
static __device__ __forceinline__ unsigned short f2bf_hw(float f) {
    return __builtin_bit_cast(unsigned short, (__bf16)f);
}
static __device__ __forceinline__ unsigned int packbf(float lo, float hi) {
    return (unsigned int)f2bf_hw(lo) | ((unsigned int)f2bf_hw(hi) << 16);
}
static __device__ __forceinline__ bf16x8 bload(const unsigned short* p) {
    return __builtin_bit_cast(bf16x8, *(const ushort8_t*)p);
}

// fast exp2 -> v_exp_f32
#if defined(__has_builtin)
#if __has_builtin(__builtin_amdgcn_exp2f)
#define HAVE_EXP2_BUILTIN 1
#endif
#endif
static __device__ __forceinline__ float fexp2(float x) {
#ifdef HAVE_EXP2_BUILTIN
    return __builtin_amdgcn_exp2f(x);
#else
    float r; asm("v_exp_f32 %0, %1" : "=v"(r) : "v"(x)); return r;
#endif
}

// ---- async global->LDS (16B per lane; LDS dest wave-uniform base + lane*16) ----
typedef __attribute__((address_space(1))) const unsigned int gu32;
typedef __attribute__((address_space(3))) unsigned int lu32;
static __device__ __forceinline__ void gld16(const void* g, void* l) {
    __builtin_amdgcn_global_load_lds((gu32*)g, (lu32*)l, 16, 0, 0);
}

#define VMCNT(n) asm volatile("s_waitcnt vmcnt(" #n ")" ::: "memory")
#define LGKM0    asm volatile("s_waitcnt lgkmcnt(0)" ::: "memory")

// ---------------- cast x -> bf16 ----------------
__global__ void cast_x_kernel(const float* __restrict__ in,
                              unsigned short* __restrict__ out, int n4) {
    int idx = blockIdx.x * blockDim.x + threadIdx.x;
    int stride = gridDim.x * blockDim.x;
    for (int i = idx; i < n4; i += stride) {
        float4 v = ((const float4*)in)[i];
        ushort4_t o;
        o.x = f2bf(v.x); o.y = f2bf(v.y); o.z = f2bf(v.z); o.w = f2bf(v.w);
        ((ushort4_t*)out)[i] = o;
    }
}

// ------------- transpose f32[K][N] -> bf16[N][K] -------------
__global__ void transpose_cast_kernel(const float* __restrict__ in,
                                      unsigned short* __restrict__ out,
                                      int K, int N) {
    __shared__ float tile[32][33];
    int tx = threadIdx.x & 31;
    int ty = threadIdx.x >> 5;
    int n0 = blockIdx.x * 32;
    int k0 = blockIdx.y * 32;
#pragma unroll
    for (int rr = 0; rr < 32; rr += 8)
        tile[ty + rr][tx] = in[(size_t)(k0 + ty + rr) * N + n0 + tx];
    __syncthreads();
#pragma unroll
    for (int rr = 0; rr < 32; rr += 8)
        out[(size_t)(n0 + ty + rr) * K + k0 + tx] = f2bf(tile[tx][ty + rr]);
}

// =================== GEMM common body (dbuf LDS via global_load_lds) ===================
// Granule XOR-swizzle: LDS slot s of row r holds global granule s ^ ((r>>1)&3);
// quad index (4r + slot) % 8 covers all 8 quads over any 8 fragment rows ->
// conflict-free ds_read_b128. Source pre-swizzled, dest linear (rule #21).

#define GEMM_PROLOGUE(BXE, BYE)                                                          \
    __shared__ unsigned short As[2][128 * 32];                                           \
    __shared__ unsigned short Bs[2][128 * 32];                                           \
    const int tid = threadIdx.x;                                                         \
    const int lane = tid & 63;                                                           \
    const int wave = tid >> 6;                                                           \
    const int g = lane >> 4, cl = lane & 15;                                             \
    const int wr = (wave >> 1) * 64, wc = (wave & 1) * 64;                               \
    const int row0 = (BXE) * 128;                                                        \
    const int col0 = (BYE) * 128;                                                        \
    const int srow = tid >> 2;  /* 0..63 */                                              \
    const int sgran = tid & 3;                                                           \
    f32x4 acc[4][4];                                                                     \
    _Pragma("unroll") for (int m = 0; m < 4; ++m)                                        \
        _Pragma("unroll") for (int n = 0; n < 4; ++n)                                    \
            acc[m][n] = (f32x4){0.f, 0.f, 0.f, 0.f};                                     \
    auto stage = [&](int buf, int k0) {                                                  \
        _Pragma("unroll") for (int c = 0; c < 2; ++c) {                                  \
            int r = srow + c * 64;                                                       \
            int lg = sgran ^ ((r >> 1) & 3);                                             \
            gld16(A + (size_t)(row0 + r) * K_ + k0 + lg * 8,                             \
                  (char*)&As[buf][0] + c * 4096 + wave * 1024);                          \
            gld16(Bt + (size_t)(col0 + r) * K_ + k0 + lg * 8,                            \
                  (char*)&Bs[buf][0] + c * 4096 + wave * 1024);                          \
        }                                                                                \
    };                                                                                   \
    stage(0, 0);                                                                         \
    int buf = 0;                                                                         \
    for (int k0 = 0; k0 < K_; k0 += 32) {                                                \
        if (k0 + 32 < K_) { stage(buf ^ 1, k0 + 32); VMCNT(4); }                         \
        else              { VMCNT(0); }                                                  \
        __builtin_amdgcn_s_barrier();                                                    \
        bf16x8 af[4], bfv[4];                                                            \
        _Pragma("unroll") for (int m = 0; m < 4; ++m) {                                  \
            int ra = wr + m * 16 + cl;                                                   \
            af[m] = bload(&As[buf][ra * 32 + (g ^ ((ra >> 1) & 3)) * 8]);                \
        }                                                                                \
        _Pragma("unroll") for (int n = 0; n < 4; ++n) {                                  \
            int rb = wc + n * 16 + cl;                                                   \
            bfv[n] = bload(&Bs[buf][rb * 32 + (g ^ ((rb >> 1) & 3)) * 8]);               \
        }                                                                                \
        _Pragma("unroll") for (int m = 0; m < 4; ++m)                                    \
            _Pragma("unroll") for (int n = 0; n < 4; ++n)                                \
                acc[m][n] = __builtin_amdgcn_mfma_f32_16x16x32_bf16(                     \
                    af[m], bfv[n], acc[m][n], 0, 0, 0);                                  \
        LGKM0;                                                                           \
        __builtin_amdgcn_s_barrier();                                                    \
        buf ^= 1;                                                                        \
    }

// ---------------- GEMM1: qkv = Xb @ Wt1^T + b ----------------
__global__ __launch_bounds__(256)
void gemm_qkv_kernel(const unsigned short* __restrict__ A,   // [4096][1024] bf16
                     const unsigned short* __restrict__ Bt,  // [3072][1024] bf16
                     const float* __restrict__ bias,         // [3072]
                     unsigned short* __restrict__ Qo,        // [BH][T][D] (pre-scaled)
                     unsigned short* __restrict__ Ko,        // [BH][T][D]
                     unsigned short* __restrict__ Vt)        // [BH][D][T]
{
    const int lin = blockIdx.x + gridDim.x * blockIdx.y;  // 0..767
    const int xcd = lin & 7;
    const int idx = lin >> 3;                              // 0..95
    const int bx = (xcd >> 1) * 8 + (idx & 7);             // 0..31
    const int by = (xcd & 1) * 12 + (idx >> 3);            // 0..23

    GEMM_PROLOGUE(bx, by)

    const float QSCALE = 0.125f * 1.44269504088896340736f;  // 1/sqrt(D) * log2(e)
#pragma unroll
    for (int m = 0; m < 4; ++m) {
        int i0 = row0 + wr + m * 16 + g * 4;
        int b = i0 >> 11, t0 = i0 & 2047;   // 4 consecutive t from t0 (same b)
#pragma unroll
        for (int n = 0; n < 4; ++n) {
            int j = col0 + wc + n * 16 + cl;
            int which = j >> 10;
            int c = j & 1023;
            int h = c >> 6, d = c & 63;
            float bv = bias[j];
            size_t bh = (size_t)(b * H_ + h);
            float v0 = acc[m][n][0] + bv;
            float v1 = acc[m][n][1] + bv;
            float v2 = acc[m][n][2] + bv;
            float v3 = acc[m][n][3] + bv;
            if (which == 2) {
                uint2_t w;
                w.x = packbf(v0, v1);
                w.y = packbf(v2, v3);
                *(uint2_t*)&Vt[(bh * D_ + d) * T_ + t0] = w;
            } else if (which == 0) {
                Qo[(bh * T_ + t0 + 0) * D_ + d] = f2bf_hw(v0 * QSCALE);
                Qo[(bh * T_ + t0 + 1) * D_ + d] = f2bf_hw(v1 * QSCALE);
                Qo[(bh * T_ + t0 + 2) * D_ + d] = f2bf_hw(v2 * QSCALE);
                Qo[(bh * T_ + t0 + 3) * D_ + d] = f2bf_hw(v3 * QSCALE);
            } else {
                Ko[(bh * T_ + t0 + 0) * D_ + d] = f2bf_hw(v0);
                Ko[(bh * T_ + t0 + 1) * D_ + d] = f2bf_hw(v1);
                Ko[(bh * T_ + t0 + 2) * D_ + d] = f2bf_hw(v2);
                Ko[(bh * T_ + t0 + 3) * D_ + d] = f2bf_hw(v3);
            }
        }
    }
}

// ---------------- GEMM2: out = AO @ Wt2^T + b (fp32 out) ----------------
__global__ __launch_bounds__(256)
void gemm_proj_kernel(const unsigned short* __restrict__ A,   // [4096][1024] bf16
                      const unsigned short* __restrict__ Bt,  // [1024][1024] bf16
                      const float* __restrict__ bias,         // [1024]
                      float* __restrict__ out)                // [4096][1024] f32
{
    GEMM_PROLOGUE(blockIdx.x, blockIdx.y)

#pragma unroll
    for (int m = 0; m < 4; ++m) {
        int i0 = row0 + wr + m * 16 + g * 4;
#pragma unroll
        for (int n = 0; n < 4; ++n) {
            int j = col0 + wc + n * 16 + cl;
            float bv = bias[j];
#pragma unroll
            for (int r = 0; r < 4; ++r)
                out[(size_t)(i0 + r) * C_ + j] = acc[m][n][r] + bv;
        }
    }
}

// ---------------- flash attention (causal, swapped QK^T, 4 blocks/CU) ----------------
// grid 1024 (1-D): xcd = lin&7; bh = xcd + 8*(idx&3) -> 4 heads/XCD (L2-resident);
// qt = 31-(idx>>2) -> longest tiles dispatch first. LDS 40960 B = 4 blocks/CU.
// Swapped operands: lane owns q-row. LANE-LOCAL online softmax: l_part kept
// per-lane (reduced once at epilogue); cross-lane shfl only on (rare) rescale.
// Common-path chain: MFMA -> exp2 -> pack -> P-LDS -> MFMA. Defer-max THR=8.
__global__ __launch_bounds__(256)
void attn_kernel(const unsigned short* __restrict__ Q,   // [BH][T][D], pre-scaled
                 const unsigned short* __restrict__ Kb,  // [BH][T][D]
                 const unsigned short* __restrict__ Vh_, // [BH][D][T]
                 unsigned short* __restrict__ AO)        // [B][T][C] bf16
{
    __shared__ unsigned short Klds[2][64 * 64];   // 16 KB
    __shared__ unsigned short Vlds[2][64 * 64];   // 16 KB
    __shared__ unsigned short Plds[4][16 * 64];   // 8 KB, XOR-swizzled rows
    const int lin = blockIdx.x;                   // 0..1023
    const int idx = lin >> 3;                     // 0..127
    const int bh  = (lin & 7) + 8 * (idx & 3);    // 0..31, head pinned to one XCD
    const int qt  = 31 - (idx >> 2);              // long tiles first
    const int b = bh >> 4, h = bh & 15;
    const int tid = threadIdx.x;
    const int lane = tid & 63;
    const int wave = tid >> 6;
    const int g = lane >> 4, cl = lane & 15;

    const unsigned short* Qh = Q + (size_t)bh * T_ * D_;
    const unsigned short* Kh = Kb + (size_t)bh * T_ * D_;
    const unsigned short* Vh = Vh_ + (size_t)bh * D_ * T_;

    const int srow = tid >> 3;  // 0..31
    const int sg   = tid & 7;
    const int pswz = (cl & 7) << 4;   // Plds byte-XOR (same involution write & read)

    auto stage = [&](int bufi, int kb) {
#pragma unroll
        for (int c = 0; c < 2; ++c) {
            int r = srow + c * 32;
            int lg = sg ^ (r & 7);
            gld16(Kh + (size_t)(kb + r) * D_ + lg * 8,
                  (char*)&Klds[bufi][0] + c * 4096 + wave * 1024);
            gld16(Vh + (size_t)r * T_ + kb + lg * 8,
                  (char*)&Vlds[bufi][0] + c * 4096 + wave * 1024);
        }
    };

    const int q0 = qt * 64 + wave * 16;
    const int tq = q0 + cl;   // this lane's q row

    bf16x8 qf[2];
#pragma unroll
    for (int c2 = 0; c2 < 2; ++c2)
        qf[c2] = bload(Qh + (size_t)(q0 + cl) * D_ + c2 * 32 + g * 8);

    f32x4 oacc[4];
#pragma unroll
    for (int n = 0; n < 4; ++n) oacc[n] = (f32x4){0.f, 0.f, 0.f, 0.f};
    float m_run = -INFINITY;   // row-consistent (only updated under reduction)
    float l_part = 0.f;        // LANE-LOCAL partial; reduced at epilogue

    const int nk = qt + 1;
    stage(0, 0);
    int buf = 0;
    for (int kt = 0; kt < nk; ++kt) {
        if (kt + 1 < nk) { stage(buf ^ 1, (kt + 1) * 64); VMCNT(4); }
        else             { VMCNT(0); }
        __builtin_amdgcn_s_barrier();

        const int kb = kt * 64;
        // ---- QK^T (swapped): sc[n] row = k, col = q ----
        f32x4 sc[4];
        __builtin_amdgcn_s_setprio(1);
#pragma unroll
        for (int n = 0; n < 4; ++n) {
            sc[n] = (f32x4){0.f, 0.f, 0.f, 0.f};
#pragma unroll
            for (int c2 = 0; c2 < 2; ++c2) {
                int pg = (c2 * 4 + g) ^ (cl & 7);
                bf16x8 kf = bload(&Klds[buf][(n * 16 + cl) * 64 + pg * 8]);
                sc[n] = __builtin_amdgcn_mfma_f32_16x16x32_bf16(kf, qf[c2], sc[n], 0, 0, 0);
            }
        }
        __builtin_amdgcn_s_setprio(0);
        // ---- causal mask (diagonal tile only); k = kb + n*16 + g*4 + r ----
        if (kt == qt) {
#pragma unroll
            for (int n = 0; n < 4; ++n) {
                int k4 = kb + n * 16 + g * 4;
#pragma unroll
                for (int r = 0; r < 4; ++r)
                    if (k4 + r > tq) sc[n][r] = -INFINITY;
            }
        }
        // ---- lane-local online softmax (defer-max THR=8, cross-lane only on rescale) ----
        float mx[4];
#pragma unroll
        for (int n = 0; n < 4; ++n)
            mx[n] = fmaxf(fmaxf(sc[n][0], sc[n][1]), fmaxf(sc[n][2], sc[n][3]));
        float lm = fmaxf(fmaxf(mx[0], mx[1]), fmaxf(mx[2], mx[3]));
        if (!__all(lm <= m_run + 8.f)) {
            float vmax = lm;
            vmax = fmaxf(vmax, __shfl_xor(vmax, 16, 64));
            vmax = fmaxf(vmax, __shfl_xor(vmax, 32, 64));
            float mn = fmaxf(m_run, vmax);
            float alpha = fexp2(m_run - mn);
            l_part *= alpha;
#pragma unroll
            for (int n = 0; n < 4; ++n)
#pragma unroll
                for (int r = 0; r < 4; ++r) oacc[n][r] *= alpha;
            m_run = mn;
        }
        float p[4][4], psub[4];
#pragma unroll
        for (int n = 0; n < 4; ++n) {
#pragma unroll
            for (int r = 0; r < 4; ++r) p[n][r] = fexp2(sc[n][r] - m_run);
            psub[n] = (p[n][0] + p[n][1]) + (p[n][2] + p[n][3]);
        }
        l_part += (psub[0] + psub[1]) + (psub[2] + psub[3]);
        // ---- P: pack bf16 pairs, 4x ds_write_b64 into own (swizzled) q-row ----
#pragma unroll
        for (int n = 0; n < 4; ++n) {
            uint2_t w;
            w.x = packbf(p[n][0], p[n][1]);
            w.y = packbf(p[n][2], p[n][3]);
            *(uint2_t*)((char*)&Plds[wave][0] + ((cl * 128 + n * 32 + g * 8) ^ pswz)) = w;
        }
        bf16x8 pf[2];
#pragma unroll
        for (int kk = 0; kk < 2; ++kk)
            pf[kk] = bload((const unsigned short*)
                ((char*)&Plds[wave][0] + ((cl * 128 + kk * 64 + g * 16) ^ pswz)));
        // ---- PV (swapped): O^T += mfma(V^T-frag, P^T-frag) ----
        __builtin_amdgcn_s_setprio(1);
#pragma unroll
        for (int n = 0; n < 4; ++n) {
#pragma unroll
            for (int kk = 0; kk < 2; ++kk) {
                int pg = (kk * 4 + g) ^ (cl & 7);
                bf16x8 vfr = bload(&Vlds[buf][(n * 16 + cl) * 64 + pg * 8]);
                oacc[n] = __builtin_amdgcn_mfma_f32_16x16x32_bf16(vfr, pf[kk], oacc[n], 0, 0, 0);
            }
        }
        __builtin_amdgcn_s_setprio(0);
        LGKM0;
        __builtin_amdgcn_s_barrier();
        buf ^= 1;
    }
    // ---- epilogue: reduce l across the 4 g-lanes of the row, then store ----
    float lt = l_part;
    lt += __shfl_xor(lt, 16, 64);
    lt += __shfl_xor(lt, 32, 64);
    float inv = 1.f / lt;
#pragma unroll
    for (int n = 0; n < 4; ++n) {
        uint2_t w;
        w.x = packbf(oacc[n][0] * inv, oacc[n][1] * inv);
        w.y = packbf(oacc[n][2] * inv, oacc[n][3] * inv);
        *(uint2_t*)&AO[((size_t)b * T_ + tq) * C_ + h * D_ + n * 16 + g * 4] = w;
    }
}

extern "C" void kernel_launch(void* const* d_in, const int* in_sizes, int n_in,
                              void* d_out, int out_size, void* d_ws, size_t ws_size,
                              hipStream_t stream) {
    (void)in_sizes; (void)n_in; (void)out_size; (void)ws_size;
    const float* x      = (const float*)d_in[0];
    const float* w_attn = (const float*)d_in[1];
    const float* b_attn = (const float*)d_in[2];
    const float* w_proj = (const float*)d_in[3];
    const float* b_proj = (const float*)d_in[4];
    float* out = (float*)d_out;

    char* ws = (char*)d_ws;
    unsigned short* Xb  = (unsigned short*)(ws);
    unsigned short* Wt1 = (unsigned short*)(ws + ((size_t)8  << 20));
    unsigned short* Wt2 = (unsigned short*)(ws + ((size_t)14 << 20));
    unsigned short* Qb  = (unsigned short*)(ws + ((size_t)16 << 20));
    unsigned short* Kb  = (unsigned short*)(ws + ((size_t)24 << 20));
    unsigned short* Vt  = (unsigned short*)(ws + ((size_t)32 << 20));
    unsigned short* AO  = Xb;  // Xb dead after gemm_qkv

    cast_x_kernel<<<1024, 256, 0, stream>>>(x, Xb, (M1 * K_) / 4);
    transpose_cast_kernel<<<dim3(N1 / 32, K_ / 32), 256, 0, stream>>>(w_attn, Wt1, K_, N1);
    transpose_cast_kernel<<<dim3(C_ / 32, K_ / 32), 256, 0, stream>>>(w_proj, Wt2, K_, C_);
    gemm_qkv_kernel<<<dim3(M1 / 128, N1 / 128), 256, 0, stream>>>(Xb, Wt1, b_attn, Qb, Kb, Vt);
    attn_kernel<<<1024, 256, 0, stream>>>(Qb, Kb, Vt, AO);
    gemm_proj_kernel<<<dim3(M1 / 128, C_ / 128), 256, 0, stream>>>(AO, Wt2, b_proj, out);
}